// Round 3
// baseline (988.951 us; speedup 1.0000x reference)
//
#include <hip/hip_runtime.h>
#include <hip/hip_bf16.h>

#define S 4096
#define DM 768
#define NH 12
#define DK 64
#define KSPLIT 2
#define KHALF (S / KSPLIT)

typedef __bf16 bf16x8 __attribute__((ext_vector_type(8)));
typedef __bf16 bf16x4 __attribute__((ext_vector_type(4)));
typedef float f32x4 __attribute__((ext_vector_type(4)));
using bf16 = __hip_bfloat16;

__device__ inline bf16x8 load_frag(const bf16* p) {
    return *reinterpret_cast<const bf16x8*>(p);
}

// Detect input dtype (f32 vs bf16) from bit patterns; flag=1 -> f32.
__global__ void k_detect(const unsigned int* __restrict__ q, int* __restrict__ flag) {
    const int lane = threadIdx.x;  // 64 threads
    int cnt = 0;
    for (int i = lane; i < 1024; i += 64) {
        const unsigned int w = q[i];
        const int e = (w >> 7) & 0xFF;
        if (e >= 192 || (e > 0 && e < 64)) cnt++;
    }
    for (int m = 1; m < 64; m <<= 1) cnt += __shfl_xor(cnt, m, 64);
    if (lane == 0) flag[0] = (cnt > 64) ? 1 : 0;
}

__global__ __launch_bounds__(256) void k_cast(const void* __restrict__ src,
                                              bf16* __restrict__ dst, int n,
                                              const int* __restrict__ flag) {
    const int isf32 = flag[0];
    const int stride = gridDim.x * 256 * 8;
    for (int i = (blockIdx.x * 256 + threadIdx.x) * 8; i < n; i += stride) {
        if (isf32) {
            const float* s = (const float*)src + i;
            float4 a = *(const float4*)(s);
            float4 b = *(const float4*)(s + 4);
            bf16x8 o;
            o[0] = (__bf16)a.x; o[1] = (__bf16)a.y; o[2] = (__bf16)a.z; o[3] = (__bf16)a.w;
            o[4] = (__bf16)b.x; o[5] = (__bf16)b.y; o[6] = (__bf16)b.z; o[7] = (__bf16)b.w;
            *reinterpret_cast<bf16x8*>(dst + i) = o;
        } else {
            *reinterpret_cast<bf16x8*>(dst + i) =
                *reinterpret_cast<const bf16x8*>((const __bf16*)src + i);
        }
    }
}

// x @ W^T + b. mode 0/1: head-split [H][S][DK]; mode 2: transposed [DM][S];
// mode 3: row-major [S][DM], dtype per flag.
__global__ __launch_bounds__(256) void k_proj(
    const bf16* __restrict__ X, const bf16* __restrict__ W,
    const bf16* __restrict__ bias, void* __restrict__ dstv, int mode,
    const int* __restrict__ flag)
{
    const int isf32 = flag[0];
    const int lane = threadIdx.x & 63;
    const int w    = threadIdx.x >> 6;
    const int lr   = lane & 15, lg = lane >> 4;
    const int rbase = blockIdx.x * 64 + w * 16;
    const int nbase = blockIdx.y * 64;

    f32x4 acc[4] = {};
    const bf16* xrow = X + (size_t)(rbase + lr) * DM + lg * 8;
    for (int kk = 0; kk < DM; kk += 32) {
        bf16x8 a = load_frag(xrow + kk);
#pragma unroll
        for (int nt = 0; nt < 4; ++nt) {
            bf16x8 b = load_frag(W + (size_t)(nbase + nt * 16 + lr) * DM + kk + lg * 8);
            acc[nt] = __builtin_amdgcn_mfma_f32_16x16x32_bf16(a, b, acc[nt], 0, 0, 0);
        }
    }
#pragma unroll
    for (int nt = 0; nt < 4; ++nt) {
        const int col = nbase + nt * 16 + lr;
        const float bv = __bfloat162float(bias[col]);
#pragma unroll
        for (int r = 0; r < 4; ++r) {
            const int row = rbase + lg * 4 + r;
            const float v = acc[nt][r] + bv;
            if (mode == 3) {
                const size_t off = (size_t)row * DM + col;
                if (isf32) ((float*)dstv)[off] = v;
                else       ((bf16*)dstv)[off] = __float2bfloat16(v);
            } else {
                size_t off;
                if (mode == 2) off = (size_t)col * S + row;
                else           off = (size_t)(col >> 6) * (S * DK) + (size_t)row * DK + (col & 63);
                ((bf16*)dstv)[off] = __float2bfloat16(v);
            }
        }
    }
}

// Partial row sums of exp(scores/8) over this block's k-half.
// Swapped MFMA: D rows = k, cols = q -> lane owns q = q0+lr.
__global__ __launch_bounds__(256) void k_rowsum(
    const bf16* __restrict__ qh, const bf16* __restrict__ kh,
    float* __restrict__ rs)
{
    const int lane = threadIdx.x & 63;
    const int w    = threadIdx.x >> 6;
    const int lr   = lane & 15, lg = lane >> 4;
    const int h    = blockIdx.y;
    const int half = blockIdx.z;
    const int q0   = blockIdx.x * 64 + w * 16;

    const bf16* qb = qh + (size_t)h * (S * DK);
    const bf16* kb = kh + (size_t)h * (S * DK);
    const bf16x8 aq0 = load_frag(qb + (size_t)(q0 + lr) * DK + lg * 8);
    const bf16x8 aq1 = load_frag(qb + (size_t)(q0 + lr) * DK + 32 + lg * 8);

    float s = 0.f;
    for (int kp = half * KHALF; kp < half * KHALF + KHALF; kp += 16) {
        bf16x8 b0 = load_frag(kb + (size_t)(kp + lr) * DK + lg * 8);
        bf16x8 b1 = load_frag(kb + (size_t)(kp + lr) * DK + 32 + lg * 8);
        f32x4 d = {};
        d = __builtin_amdgcn_mfma_f32_16x16x32_bf16(b0, aq0, d, 0, 0, 0);
        d = __builtin_amdgcn_mfma_f32_16x16x32_bf16(b1, aq1, d, 0, 0, 0);
        s += __expf(d[0] * 0.125f) + __expf(d[1] * 0.125f) +
             __expf(d[2] * 0.125f) + __expf(d[3] * 0.125f);
    }
    s += __shfl_xor(s, 16, 64);
    s += __shfl_xor(s, 32, 64);
    if (lane < 16)
        rs[(size_t)half * NH * S + (size_t)h * S + q0 + lr] = s;
}

// Recompute scores (swapped), write normalized P (float4/bf16x4 per lane),
// accumulate partial ctx = P @ V over this block's k-half.
__global__ __launch_bounds__(256) void k_attn(
    const bf16* __restrict__ qh, const bf16* __restrict__ kh,
    const bf16* __restrict__ vt, const float* __restrict__ rs,
    void* __restrict__ doutv, bf16* __restrict__ ctxp,
    const int* __restrict__ flag)
{
    __shared__ __align__(16) bf16 Plds[4][16][72];
    const int isf32 = flag[0];
    const int lane = threadIdx.x & 63;
    const int w    = threadIdx.x >> 6;
    const int lr   = lane & 15, lg = lane >> 4;
    const int h    = blockIdx.y;
    const int half = blockIdx.z;
    const int q0   = blockIdx.x * 64 + w * 16;
    const int k0   = half * KHALF;

    const bf16* qb = qh + (size_t)h * (S * DK);
    const bf16* kb = kh + (size_t)h * (S * DK);
    const bf16* vb = vt + (size_t)h * (S * DK);
    const bf16x8 aq0 = load_frag(qb + (size_t)(q0 + lr) * DK + lg * 8);
    const bf16x8 aq1 = load_frag(qb + (size_t)(q0 + lr) * DK + 32 + lg * 8);

    const float inv_s = 1.0f / (rs[(size_t)h * S + q0 + lr] +
                                rs[(size_t)NH * S + (size_t)h * S + q0 + lr]);

    float* poutF = (float*)doutv + (size_t)S * DM + (size_t)h * S * S;
    bf16*  poutB = (bf16*)doutv  + (size_t)S * DM + (size_t)h * S * S;

    f32x4 acc[4] = {};
    for (int kt = k0; kt < k0 + KHALF; kt += 64) {
#pragma unroll
        for (int sub = 0; sub < 4; ++sub) {
            const int kp = kt + sub * 16;
            bf16x8 b0 = load_frag(kb + (size_t)(kp + lr) * DK + lg * 8);
            bf16x8 b1 = load_frag(kb + (size_t)(kp + lr) * DK + 32 + lg * 8);
            f32x4 d = {};
            d = __builtin_amdgcn_mfma_f32_16x16x32_bf16(b0, aq0, d, 0, 0, 0);
            d = __builtin_amdgcn_mfma_f32_16x16x32_bf16(b1, aq1, d, 0, 0, 0);
            const float p0 = __expf(d[0] * 0.125f) * inv_s;
            const float p1 = __expf(d[1] * 0.125f) * inv_s;
            const float p2 = __expf(d[2] * 0.125f) * inv_s;
            const float p3 = __expf(d[3] * 0.125f) * inv_s;
            bf16x4 pv;
            pv[0] = (__bf16)p0; pv[1] = (__bf16)p1;
            pv[2] = (__bf16)p2; pv[3] = (__bf16)p3;
            const size_t off = (size_t)(q0 + lr) * S + kp + 4 * lg;
            if (isf32) {
                float4 f4; f4.x = p0; f4.y = p1; f4.z = p2; f4.w = p3;
                *reinterpret_cast<float4*>(poutF + off) = f4;
            } else {
                *reinterpret_cast<bf16x4*>(poutB + off) = pv;
            }
            *reinterpret_cast<bf16x4*>(&Plds[w][lr][sub * 16 + 4 * lg]) = pv;
        }
        bf16x8 ap0 = *reinterpret_cast<const bf16x8*>(&Plds[w][lr][lg * 8]);
        bf16x8 ap1 = *reinterpret_cast<const bf16x8*>(&Plds[w][lr][32 + lg * 8]);
#pragma unroll
        for (int dt = 0; dt < 4; ++dt) {
            bf16x8 v0 = load_frag(vb + (size_t)(dt * 16 + lr) * S + kt + lg * 8);
            bf16x8 v1 = load_frag(vb + (size_t)(dt * 16 + lr) * S + kt + 32 + lg * 8);
            acc[dt] = __builtin_amdgcn_mfma_f32_16x16x32_bf16(ap0, v0, acc[dt], 0, 0, 0);
            acc[dt] = __builtin_amdgcn_mfma_f32_16x16x32_bf16(ap1, v1, acc[dt], 0, 0, 0);
        }
    }
    bf16* cp = ctxp + (size_t)half * S * DM;
#pragma unroll
    for (int dt = 0; dt < 4; ++dt)
#pragma unroll
        for (int r = 0; r < 4; ++r)
            cp[(size_t)(q0 + 4 * lg + r) * DM + h * DK + dt * 16 + lr] =
                __float2bfloat16(acc[dt][r]);
}

// ctx = ctxp[0] + ctxp[1] (bf16)
__global__ __launch_bounds__(256) void k_reduce(const bf16* __restrict__ ctxp,
                                               bf16* __restrict__ ctx) {
    const int i = (blockIdx.x * 256 + threadIdx.x) * 8;
    bf16x8 a = *reinterpret_cast<const bf16x8*>(ctxp + i);
    bf16x8 b = *reinterpret_cast<const bf16x8*>(ctxp + (size_t)S * DM + i);
    bf16x8 o;
#pragma unroll
    for (int j = 0; j < 8; ++j) o[j] = (__bf16)((float)a[j] + (float)b[j]);
    *reinterpret_cast<bf16x8*>(ctx + i) = o;
}

extern "C" void kernel_launch(void* const* d_in, const int* in_sizes, int n_in,
                              void* d_out, int out_size, void* d_ws, size_t ws_size,
                              hipStream_t stream) {
    char* wsb = (char*)d_ws;
    int*   flag = (int*)wsb;                                   // 16 B
    float* rs   = (float*)(wsb + 16);                          // 2*NH*S f32
    bf16*  conv = (bf16*)(wsb + 16 + (size_t)2 * NH * S * 4);

    const size_t nQ = (size_t)S * DM, nW = (size_t)DM * DM, nB = DM;
    bf16* Qc  = conv;
    bf16* Kc  = Qc + nQ;
    bf16* Vc  = Kc + nQ;
    bf16* Wqc = Vc + nQ;
    bf16* Wkc = Wqc + nW;
    bf16* Wvc = Wkc + nW;
    bf16* Woc = Wvc + nW;
    bf16* bqc = Woc + nW;
    bf16* bkc = bqc + nB;
    bf16* bvc = bkc + nB;
    bf16* boc = bvc + nB;
    bf16* qh  = boc + nB;
    bf16* kh  = qh + nQ;
    bf16* vt  = kh + nQ;
    // aliases (Qc/Kc/Vc are dead after the projections):
    bf16* ctxp = Qc;   // 2*nQ bf16 partial ctx
    bf16* ctx  = Vc;   // nQ bf16 summed ctx

    const size_t need = (size_t)((char*)(vt + nQ) - wsb);
    if (ws_size < need) return;

    dim3 blk(256);
    k_detect<<<1, 64, 0, stream>>>((const unsigned int*)d_in[0], flag);

    const void* srcs[11] = {d_in[0], d_in[1], d_in[2], d_in[3], d_in[4], d_in[5],
                            d_in[6], d_in[7], d_in[8], d_in[9], d_in[10]};
    bf16* dsts[11] = {Qc, Kc, Vc, Wqc, bqc, Wkc, bkc, Wvc, bvc, Woc, boc};
    const int ns[11] = {(int)nQ, (int)nQ, (int)nQ, (int)nW, (int)nB, (int)nW,
                        (int)nB, (int)nW, (int)nB, (int)nW, (int)nB};
    for (int t = 0; t < 11; ++t) {
        int blocks = (ns[t] / 8 + 255) / 256;
        k_cast<<<blocks, blk, 0, stream>>>(srcs[t], dsts[t], ns[t], flag);
    }

    k_proj<<<dim3(S / 64, DM / 64), blk, 0, stream>>>(Qc, Wqc, bqc, qh, 0, flag);
    k_proj<<<dim3(S / 64, DM / 64), blk, 0, stream>>>(Kc, Wkc, bkc, kh, 1, flag);
    k_proj<<<dim3(S / 64, DM / 64), blk, 0, stream>>>(Vc, Wvc, bvc, vt, 2, flag);
    k_rowsum<<<dim3(S / 64, NH, KSPLIT), blk, 0, stream>>>(qh, kh, rs);
    k_attn<<<dim3(S / 64, NH, KSPLIT), blk, 0, stream>>>(qh, kh, vt, rs, d_out, ctxp, flag);
    k_reduce<<<dim3((int)(nQ / 8 / 256)), blk, 0, stream>>>(ctxp, ctx);
    k_proj<<<dim3(S / 64, DM / 64), blk, 0, stream>>>(ctx, Woc, boc, d_out, 3, flag);
}

// Round 5
// 757.557 us; speedup vs baseline: 1.3054x; 1.3054x over previous
//
#include <hip/hip_runtime.h>
#include <hip/hip_bf16.h>

#define S 4096
#define DM 768
#define NH 12
#define DK 64
#define KSPLIT 2
#define KHALF (S / KSPLIT)

typedef __bf16 bf16x8 __attribute__((ext_vector_type(8)));
typedef __bf16 bf16x4 __attribute__((ext_vector_type(4)));
typedef float f32x4 __attribute__((ext_vector_type(4)));
using bf16 = __hip_bfloat16;

__device__ inline bf16x8 load_frag(const bf16* p) {
    return *reinterpret_cast<const bf16x8*>(p);
}

// Detect input dtype (f32 vs bf16) from bit patterns; flag=1 -> f32.
__global__ void k_detect(const unsigned int* __restrict__ q, int* __restrict__ flag) {
    const int lane = threadIdx.x;  // 64 threads
    int cnt = 0;
    for (int i = lane; i < 1024; i += 64) {
        const unsigned int w = q[i];
        const int e = (w >> 7) & 0xFF;
        if (e >= 192 || (e > 0 && e < 64)) cnt++;
    }
    for (int m = 1; m < 64; m <<= 1) cnt += __shfl_xor(cnt, m, 64);
    if (lane == 0) flag[0] = (cnt > 64) ? 1 : 0;
}

__global__ __launch_bounds__(256) void k_cast(const void* __restrict__ src,
                                              bf16* __restrict__ dst, int n,
                                              const int* __restrict__ flag) {
    const int isf32 = flag[0];
    const int stride = gridDim.x * 256 * 8;
    for (int i = (blockIdx.x * 256 + threadIdx.x) * 8; i < n; i += stride) {
        if (isf32) {
            const float* s = (const float*)src + i;
            float4 a = *(const float4*)(s);
            float4 b = *(const float4*)(s + 4);
            bf16x8 o;
            o[0] = (__bf16)a.x; o[1] = (__bf16)a.y; o[2] = (__bf16)a.z; o[3] = (__bf16)a.w;
            o[4] = (__bf16)b.x; o[5] = (__bf16)b.y; o[6] = (__bf16)b.z; o[7] = (__bf16)b.w;
            *reinterpret_cast<bf16x8*>(dst + i) = o;
        } else {
            *reinterpret_cast<bf16x8*>(dst + i) =
                *reinterpret_cast<const bf16x8*>((const __bf16*)src + i);
        }
    }
}

// x @ W^T + b. mode 0/1: head-split [H][S][DK]; mode 2: transposed [DM][S];
// mode 3: row-major [S][DM], dtype per flag.
__global__ __launch_bounds__(256) void k_proj(
    const bf16* __restrict__ X, const bf16* __restrict__ W,
    const bf16* __restrict__ bias, void* __restrict__ dstv, int mode,
    const int* __restrict__ flag)
{
    const int isf32 = flag[0];
    const int lane = threadIdx.x & 63;
    const int w    = threadIdx.x >> 6;
    const int lr   = lane & 15, lg = lane >> 4;
    const int rbase = blockIdx.x * 64 + w * 16;
    const int nbase = blockIdx.y * 64;

    f32x4 acc[4] = {};
    const bf16* xrow = X + (size_t)(rbase + lr) * DM + lg * 8;
    for (int kk = 0; kk < DM; kk += 32) {
        bf16x8 a = load_frag(xrow + kk);
#pragma unroll
        for (int nt = 0; nt < 4; ++nt) {
            bf16x8 b = load_frag(W + (size_t)(nbase + nt * 16 + lr) * DM + kk + lg * 8);
            acc[nt] = __builtin_amdgcn_mfma_f32_16x16x32_bf16(a, b, acc[nt], 0, 0, 0);
        }
    }
#pragma unroll
    for (int nt = 0; nt < 4; ++nt) {
        const int col = nbase + nt * 16 + lr;
        const float bv = __bfloat162float(bias[col]);
#pragma unroll
        for (int r = 0; r < 4; ++r) {
            const int row = rbase + lg * 4 + r;
            const float v = acc[nt][r] + bv;
            if (mode == 3) {
                const size_t off = (size_t)row * DM + col;
                if (isf32) ((float*)dstv)[off] = v;
                else       ((bf16*)dstv)[off] = __float2bfloat16(v);
            } else {
                size_t off;
                if (mode == 2) off = (size_t)col * S + row;
                else           off = (size_t)(col >> 6) * (S * DK) + (size_t)row * DK + (col & 63);
                ((bf16*)dstv)[off] = __float2bfloat16(v);
            }
        }
    }
}

// Partial row sums of exp(scores/8) over this block's k-half (swapped MFMA).
__global__ __launch_bounds__(256) void k_rowsum(
    const bf16* __restrict__ qh, const bf16* __restrict__ kh,
    float* __restrict__ rs)
{
    const int lane = threadIdx.x & 63;
    const int w    = threadIdx.x >> 6;
    const int lr   = lane & 15, lg = lane >> 4;
    const int h    = blockIdx.y;
    const int half = blockIdx.z;
    const int q0   = blockIdx.x * 64 + w * 16;

    const bf16* qb = qh + (size_t)h * (S * DK);
    const bf16* kb = kh + (size_t)h * (S * DK);
    const bf16x8 aq0 = load_frag(qb + (size_t)(q0 + lr) * DK + lg * 8);
    const bf16x8 aq1 = load_frag(qb + (size_t)(q0 + lr) * DK + 32 + lg * 8);

    float s = 0.f;
    for (int kp = half * KHALF; kp < half * KHALF + KHALF; kp += 16) {
        bf16x8 b0 = load_frag(kb + (size_t)(kp + lr) * DK + lg * 8);
        bf16x8 b1 = load_frag(kb + (size_t)(kp + lr) * DK + 32 + lg * 8);
        f32x4 d = {};
        d = __builtin_amdgcn_mfma_f32_16x16x32_bf16(b0, aq0, d, 0, 0, 0);
        d = __builtin_amdgcn_mfma_f32_16x16x32_bf16(b1, aq1, d, 0, 0, 0);
        s += __expf(d[0] * 0.125f) + __expf(d[1] * 0.125f) +
             __expf(d[2] * 0.125f) + __expf(d[3] * 0.125f);
    }
    s += __shfl_xor(s, 16, 64);
    s += __shfl_xor(s, 32, 64);
    if (lane < 16)
        rs[(size_t)half * NH * S + (size_t)h * S + q0 + lr] = s;
}

// Recompute scores (swapped), normalize, stage f32 P tile in LDS, flush with
// 256B-contiguous nontemporal stores; accumulate partial ctx = P @ V.
__global__ __launch_bounds__(256) void k_attn(
    const bf16* __restrict__ qh, const bf16* __restrict__ kh,
    const bf16* __restrict__ vt, const float* __restrict__ rs,
    void* __restrict__ doutv, bf16* __restrict__ ctxp,
    const int* __restrict__ flag)
{
    __shared__ __align__(16) bf16  Plds[4][16][72];
    __shared__ __align__(16) float Pf[4][16][68];
    const int isf32 = flag[0];
    const int lane = threadIdx.x & 63;
    const int w    = threadIdx.x >> 6;
    const int lr   = lane & 15, lg = lane >> 4;
    const int h    = blockIdx.y;
    const int half = blockIdx.z;
    const int q0   = blockIdx.x * 64 + w * 16;
    const int k0   = half * KHALF;

    const bf16* qb = qh + (size_t)h * (S * DK);
    const bf16* kb = kh + (size_t)h * (S * DK);
    const bf16* vb = vt + (size_t)h * (S * DK);
    const bf16x8 aq0 = load_frag(qb + (size_t)(q0 + lr) * DK + lg * 8);
    const bf16x8 aq1 = load_frag(qb + (size_t)(q0 + lr) * DK + 32 + lg * 8);

    const float inv_s = 1.0f / (rs[(size_t)h * S + q0 + lr] +
                                rs[(size_t)NH * S + (size_t)h * S + q0 + lr]);

    float* poutF = (float*)doutv + (size_t)S * DM + (size_t)h * S * S;
    bf16*  poutB = (bf16*)doutv  + (size_t)S * DM + (size_t)h * S * S;

    f32x4 acc[4] = {};
    for (int kt = k0; kt < k0 + KHALF; kt += 64) {
#pragma unroll
        for (int sub = 0; sub < 4; ++sub) {
            const int kp = kt + sub * 16;
            bf16x8 b0 = load_frag(kb + (size_t)(kp + lr) * DK + lg * 8);
            bf16x8 b1 = load_frag(kb + (size_t)(kp + lr) * DK + 32 + lg * 8);
            f32x4 d = {};
            d = __builtin_amdgcn_mfma_f32_16x16x32_bf16(b0, aq0, d, 0, 0, 0);
            d = __builtin_amdgcn_mfma_f32_16x16x32_bf16(b1, aq1, d, 0, 0, 0);
            f32x4 p;
            p[0] = __expf(d[0] * 0.125f) * inv_s;
            p[1] = __expf(d[1] * 0.125f) * inv_s;
            p[2] = __expf(d[2] * 0.125f) * inv_s;
            p[3] = __expf(d[3] * 0.125f) * inv_s;
            bf16x4 pv;
            pv[0] = (__bf16)p[0]; pv[1] = (__bf16)p[1];
            pv[2] = (__bf16)p[2]; pv[3] = (__bf16)p[3];
            *reinterpret_cast<bf16x4*>(&Plds[w][lr][sub * 16 + 4 * lg]) = pv;
            if (isf32) {
                *reinterpret_cast<f32x4*>(&Pf[w][lr][sub * 16 + 4 * lg]) = p;
            } else {
                const size_t off = (size_t)(q0 + lr) * S + kp + 4 * lg;
                *reinterpret_cast<bf16x4*>(poutB + off) = pv;
            }
        }
        if (isf32) {
            // flush: 4 stores, each 4 rows x 256B contiguous (lane -> column)
#pragma unroll
            for (int j = 0; j < 4; ++j) {
                f32x4 row = *reinterpret_cast<const f32x4*>(&Pf[w][4 * j + lg][4 * lr]);
                __builtin_nontemporal_store(
                    row, reinterpret_cast<f32x4*>(
                             poutF + (size_t)(q0 + 4 * j + lg) * S + kt + 4 * lr));
            }
        }
        bf16x8 ap0 = *reinterpret_cast<const bf16x8*>(&Plds[w][lr][lg * 8]);
        bf16x8 ap1 = *reinterpret_cast<const bf16x8*>(&Plds[w][lr][32 + lg * 8]);
#pragma unroll
        for (int dt = 0; dt < 4; ++dt) {
            bf16x8 v0 = load_frag(vb + (size_t)(dt * 16 + lr) * S + kt + lg * 8);
            bf16x8 v1 = load_frag(vb + (size_t)(dt * 16 + lr) * S + kt + 32 + lg * 8);
            acc[dt] = __builtin_amdgcn_mfma_f32_16x16x32_bf16(ap0, v0, acc[dt], 0, 0, 0);
            acc[dt] = __builtin_amdgcn_mfma_f32_16x16x32_bf16(ap1, v1, acc[dt], 0, 0, 0);
        }
    }
    bf16* cp = ctxp + (size_t)half * S * DM;
#pragma unroll
    for (int dt = 0; dt < 4; ++dt)
#pragma unroll
        for (int r = 0; r < 4; ++r)
            cp[(size_t)(q0 + 4 * lg + r) * DM + h * DK + dt * 16 + lr] =
                __float2bfloat16(acc[dt][r]);
}

// ctx = ctxp[0] + ctxp[1] (bf16)
__global__ __launch_bounds__(256) void k_reduce(const bf16* __restrict__ ctxp,
                                               bf16* __restrict__ ctx) {
    const int i = (blockIdx.x * 256 + threadIdx.x) * 8;
    bf16x8 a = *reinterpret_cast<const bf16x8*>(ctxp + i);
    bf16x8 b = *reinterpret_cast<const bf16x8*>(ctxp + (size_t)S * DM + i);
    bf16x8 o;
#pragma unroll
    for (int j = 0; j < 8; ++j) o[j] = (__bf16)((float)a[j] + (float)b[j]);
    *reinterpret_cast<bf16x8*>(ctx + i) = o;
}

extern "C" void kernel_launch(void* const* d_in, const int* in_sizes, int n_in,
                              void* d_out, int out_size, void* d_ws, size_t ws_size,
                              hipStream_t stream) {
    char* wsb = (char*)d_ws;
    int*   flag = (int*)wsb;                                   // 16 B
    float* rs   = (float*)(wsb + 16);                          // 2*NH*S f32
    bf16*  conv = (bf16*)(wsb + 16 + (size_t)2 * NH * S * 4);

    const size_t nQ = (size_t)S * DM, nW = (size_t)DM * DM, nB = DM;
    bf16* Qc  = conv;
    bf16* Kc  = Qc + nQ;
    bf16* Vc  = Kc + nQ;
    bf16* Wqc = Vc + nQ;
    bf16* Wkc = Wqc + nW;
    bf16* Wvc = Wkc + nW;
    bf16* Woc = Wvc + nW;
    bf16* bqc = Woc + nW;
    bf16* bkc = bqc + nB;
    bf16* bvc = bkc + nB;
    bf16* boc = bvc + nB;
    bf16* qh  = boc + nB;
    bf16* kh  = qh + nQ;
    bf16* vt  = kh + nQ;
    // aliases (Qc/Kc/Vc dead after projections):
    bf16* ctxp = Qc;   // 2*nQ bf16 partial ctx
    bf16* ctx  = Vc;   // nQ bf16 summed ctx

    const size_t need = (size_t)((char*)(vt + nQ) - wsb);
    if (ws_size < need) return;

    dim3 blk(256);
    k_detect<<<1, 64, 0, stream>>>((const unsigned int*)d_in[0], flag);

    const void* srcs[11] = {d_in[0], d_in[1], d_in[2], d_in[3], d_in[4], d_in[5],
                            d_in[6], d_in[7], d_in[8], d_in[9], d_in[10]};
    bf16* dsts[11] = {Qc, Kc, Vc, Wqc, bqc, Wkc, bkc, Wvc, bvc, Woc, boc};
    const int ns[11] = {(int)nQ, (int)nQ, (int)nQ, (int)nW, (int)nB, (int)nW,
                        (int)nB, (int)nW, (int)nB, (int)nW, (int)nB};
    for (int t = 0; t < 11; ++t) {
        int blocks = (ns[t] / 8 + 255) / 256;
        k_cast<<<blocks, blk, 0, stream>>>(srcs[t], dsts[t], ns[t], flag);
    }

    k_proj<<<dim3(S / 64, DM / 64), blk, 0, stream>>>(Qc, Wqc, bqc, qh, 0, flag);
    k_proj<<<dim3(S / 64, DM / 64), blk, 0, stream>>>(Kc, Wkc, bkc, kh, 1, flag);
    k_proj<<<dim3(S / 64, DM / 64), blk, 0, stream>>>(Vc, Wvc, bvc, vt, 2, flag);
    k_rowsum<<<dim3(S / 64, NH, KSPLIT), blk, 0, stream>>>(qh, kh, rs);
    k_attn<<<dim3(S / 64, NH, KSPLIT), blk, 0, stream>>>(qh, kh, vt, rs, d_out, ctxp, flag);
    k_reduce<<<dim3((int)(nQ / 8 / 256)), blk, 0, stream>>>(ctxp, ctx);
    k_proj<<<dim3(S / 64, DM / 64), blk, 0, stream>>>(ctx, Woc, boc, d_out, 3, flag);
}